// Round 2
// baseline (5774.006 us; speedup 1.0000x reference)
//
#include <hip/hip_runtime.h>
#include <math.h>

#define NFULL 2177   // 1 + L + S
#define NN    2176   // minor size (NFULL-1), = 17*128
#define NB    64
#define NMAT  8      // 4 batches x {z, target}
#define NBATCH 4
#define TP    65     // pitch of 64x64 factor/inverse tiles in LDS (odd -> conflict-free cols)
#define LTP   132    // Lt pitch (128 + 4)
#define UTP   140    // Ut pitch (128 + 12 skew room)
#define SSZ   8704   // floats: staging Lt[32*132]=4224 | Ut[32*140]=4480 ; factor T[64*65] | X at 4480

// ---------------- build phase ----------------

__global__ void init_cs_kernel(float* __restrict__ cs) {
  int i = blockIdx.x * blockDim.x + threadIdx.x;
  if (i < NMAT * NN) cs[i] = 0.f;
}

// Fused: writes off-diagonal M = -w for both masks while accumulating column
// sums (one atomic per thread per mask). Single pass over scores/zm/tm.
__global__ __launch_bounds__(256) void build_fused(const float* __restrict__ scores,
                                                   const float* __restrict__ zm,
                                                   const float* __restrict__ tm,
                                                   const int* __restrict__ lengths,
                                                   float* __restrict__ cs,
                                                   float* __restrict__ M) {
  int c = blockIdx.x * 256 + threadIdx.x;   // minor column, node j = c+1
  if (c >= NN) return;
  int b = blockIdx.z;
  int len = lengths[b];
  int j = c + 1;
  bool jv = (j < len);
  int r0 = blockIdx.y * 64;                 // minor row base
  size_t sbase = (size_t)b * NFULL * NFULL + j;
  float az = 0.f, at = 0.f;
  if (blockIdx.y == 0 && jv) {              // i = 0 (root row): colsum only
    float e = __expf(scores[sbase]);
    az += e * zm[sbase];
    at += e * tm[sbase];
  }
  size_t mz = (size_t)b * NN * NN + (size_t)r0 * NN + c;
  size_t mt = (size_t)(NBATCH + b) * NN * NN + (size_t)r0 * NN + c;
  for (int rr = 0; rr < 64; ++rr) {
    int i = r0 + rr + 1;
    float vz = 0.f, vt = 0.f;
    if (jv && i < len) {
      size_t off = sbase + (size_t)i * NFULL;
      float e = __expf(scores[off]);
      vz = e * zm[off];
      vt = e * tm[off];
      az += vz;
      at += vt;
    }
    M[mz] = -vz;
    M[mt] = -vt;
    mz += NN;
    mt += NN;
  }
  if (az != 0.f) atomicAdd(&cs[b * NN + c], az);
  if (at != 0.f) atomicAdd(&cs[(NBATCH + b) * NN + c], at);
}

// diagonal: M[c][c] = colsum + pad (identity row/col for invalid nodes)
__global__ void diag_fix(const int* __restrict__ lengths,
                         const float* __restrict__ cs,
                         float* __restrict__ M) {
  int idx = blockIdx.x * 256 + threadIdx.x;
  if (idx >= NMAT * NN) return;
  int mm = idx / NN, c = idx - mm * NN;
  int len = lengths[mm & 3];
  float pad = (c + 1 < len) ? 0.f : 1.f;
  M[(size_t)mm * NN * NN + (size_t)c * NN + c] = cs[idx] + pad;
}

// ---------------- LU building blocks ----------------

// Factor 64x64 block in LDS (pitch TP), L unit-lower \ U upper. 256 threads.
// Thread owns column c = tid&63, row-residue g = tid>>6 (rows r == g mod 4).
__device__ __forceinline__ void factor64(float* T, int tid) {
  int c = tid & 63, g = tid >> 6;
  for (int j = 0; j < 63; ++j) {
    float inv = 1.0f / T[j * TP + j];
    int rs = j + 1 + ((g - j - 1) & 3);   // smallest r > j with r == g (mod 4)
    if (c == j) {
      for (int r = rs; r < 64; r += 4) T[r * TP + j] *= inv;
    }
    __syncthreads();
    if (c > j) {
      float ujc = T[j * TP + c];
      for (int r = rs; r < 64; r += 4) T[r * TP + c] -= T[r * TP + j] * ujc;
    }
    __syncthreads();
  }
}

// Row-sweep triangular inverses: lane j owns column j; uniform trip counts,
// broadcast T-row reads, consecutive X reads/writes (conflict-free).
// Wave 0 only; X reused for invU then invL. No barriers inside.
__device__ __forceinline__ void invertUL(const float* T, float* X,
                                         float* __restrict__ invUg,
                                         float* __restrict__ invLg, int tid) {
  if (tid >= 64) return;
  int j = tid;
  // U^{-1}: rows bottom-up; X[t][j]=0 for j<t emerges exactly.
  for (int i = 63; i >= 0; --i) {
    float s = (j == i) ? 1.f : 0.f;
    for (int t = i + 1; t < 64; ++t) s -= T[i * TP + t] * X[t * TP + j];
    X[i * TP + j] = s / T[i * TP + i];
  }
  for (int i = 0; i < 64; ++i) invUg[i * 64 + j] = X[i * TP + j];
  // L^{-1} (unit diag): rows top-down; overwrites X rows before they are read.
  for (int i = 0; i < 64; ++i) {
    float s = (j == i) ? 1.f : 0.f;
    for (int t = 0; t < i; ++t) s -= T[i * TP + t] * X[t * TP + j];
    X[i * TP + j] = s;
  }
  for (int i = 0; i < 64; ++i) invLg[i * 64 + j] = X[i * TP + j];
}

// factor + invert diagonal block 0 (only standalone factor launch)
__global__ __launch_bounds__(256, 2) void factor0(float* __restrict__ Mb,
                                                  float* __restrict__ invUb,
                                                  float* __restrict__ invLb) {
  __shared__ float S[SSZ];
  int m = blockIdx.x, tid = threadIdx.x;
  float* A = Mb + (size_t)m * NN * NN;
  for (int idx = tid; idx < 4096; idx += 256)
    S[(idx >> 6) * TP + (idx & 63)] = A[(size_t)(idx >> 6) * NN + (idx & 63)];
  __syncthreads();
  factor64(S, tid);
  for (int idx = tid; idx < 4096; idx += 256)
    A[(size_t)(idx >> 6) * NN + (idx & 63)] = S[(idx >> 6) * TP + (idx & 63)];
  invertUL(S, S + 4480, invUb + (size_t)m * 4096, invLb + (size_t)m * 4096, tid);
}

// Panel update as GEMM: role 0 -> L21 = A21 * invU ; role 1 -> U12 = invL * A12
__global__ __launch_bounds__(256) void panel_gemm(float* __restrict__ Mb,
                                                  const float* __restrict__ invUb,
                                                  const float* __restrict__ invLb,
                                                  int k0) {
  __shared__ float Aa[64][68];  // Aa[k][r]
  __shared__ float Bb[64][68];  // Bb[k][c]
  int m = blockIdx.y, role = blockIdx.z, tid = threadIdx.x;
  float* A = Mb + (size_t)m * NN * NN;
  int obase = k0 + 64 + blockIdx.x * 64;
  if (role == 0) {
    const float* invU = invUb + (size_t)m * 4096;
    for (int idx = tid; idx < 4096; idx += 256) {
      int r = idx >> 6, k = idx & 63;
      Aa[k][r] = A[(size_t)(obase + r) * NN + (k0 + k)];
    }
    for (int idx = tid; idx < 4096; idx += 256)
      Bb[idx >> 6][idx & 63] = invU[idx];
  } else {
    const float* invL = invLb + (size_t)m * 4096;
    for (int idx = tid; idx < 4096; idx += 256) {
      int r = idx >> 6, k = idx & 63;
      Aa[k][r] = invL[(r << 6) + k];
    }
    for (int idx = tid; idx < 4096; idx += 256) {
      int k = idx >> 6, c = idx & 63;
      Bb[k][c] = A[(size_t)(k0 + k) * NN + (obase + c)];
    }
  }
  __syncthreads();
  int c0 = (tid & 15) << 2;
  int r0 = (tid >> 4) << 2;
  float acc[4][4];
#pragma unroll
  for (int i = 0; i < 4; ++i)
#pragma unroll
    for (int jj = 0; jj < 4; ++jj) acc[i][jj] = 0.f;
#pragma unroll 8
  for (int k = 0; k < 64; ++k) {
    float4 a  = *(const float4*)&Aa[k][r0];
    float4 bv = *(const float4*)&Bb[k][c0];
    acc[0][0] += a.x * bv.x; acc[0][1] += a.x * bv.y; acc[0][2] += a.x * bv.z; acc[0][3] += a.x * bv.w;
    acc[1][0] += a.y * bv.x; acc[1][1] += a.y * bv.y; acc[1][2] += a.y * bv.z; acc[1][3] += a.y * bv.w;
    acc[2][0] += a.z * bv.x; acc[2][1] += a.z * bv.y; acc[2][2] += a.z * bv.z; acc[2][3] += a.z * bv.w;
    acc[3][0] += a.w * bv.x; acc[3][1] += a.w * bv.y; acc[3][2] += a.w * bv.z; acc[3][3] += a.w * bv.w;
  }
  if (role == 0) {
#pragma unroll
    for (int i = 0; i < 4; ++i) {
      float4 v = make_float4(acc[i][0], acc[i][1], acc[i][2], acc[i][3]);
      *(float4*)&A[(size_t)(obase + r0 + i) * NN + (k0 + c0)] = v;
    }
  } else {
#pragma unroll
    for (int i = 0; i < 4; ++i) {
      float4 v = make_float4(acc[i][0], acc[i][1], acc[i][2], acc[i][3]);
      *(float4*)&A[(size_t)(k0 + r0 + i) * NN + (obase + c0)] = v;
    }
  }
}

// Trailing update A22 -= L21*U12: 128x128 tile per block, 8x8 micro per thread,
// K=64 staged in two 32-deep halves (LDS 34.8 KB). blockIdx.x = m so the 8
// special (0,0) blocks are dispatched FIRST; their fused next-diag factor +
// triangular inverses hide under the rest of the trailing update.
__global__ __launch_bounds__(256, 2) void trail_gemm(float* __restrict__ Mb,
                                                     float* __restrict__ invUb,
                                                     float* __restrict__ invLb,
                                                     int k0, int do_inv) {
  __shared__ float S[SSZ];
  int m = blockIdx.x;
  int txt = blockIdx.y, tyt = blockIdx.z;
  float* A = Mb + (size_t)m * NN * NN;
  int base = k0 + NB;
  int rem  = NN - base;
  int rbase = base + tyt * 128, cbase = base + txt * 128;
  int rows = rem - tyt * 128; if (rows > 128) rows = 128;
  int cols = rem - txt * 128; if (cols > 128) cols = 128;
  int tid = threadIdx.x;
  int tx = tid & 15, ty = tid >> 4;
  int rr = ty * 8, cc = tx * 8;
  int cs0 = cc + ((cc >> 5) << 2);   // skewed Ut column (chunks of 8 never straddle 32)
  float acc[8][8];
#pragma unroll
  for (int i = 0; i < 8; ++i)
#pragma unroll
    for (int j = 0; j < 8; ++j) acc[i][j] = 0.f;

  for (int h = 0; h < 2; ++h) {
    if (h) __syncthreads();
    int kb = k0 + h * 32;
    // Lt[k][r] (transposed): consecutive lanes -> consecutive k -> coalesced global
    for (int idx = tid; idx < 4096; idx += 256) {
      int k = idx & 31, r = idx >> 5;
      int gr = rbase + (r < rows ? r : 0);   // clamp OOB rows (acc rows unused)
      S[k * LTP + r] = A[(size_t)gr * NN + kb + k];
    }
    // Ut[k][c'] with +4-per-32 skew -> 2-way (free) bank pattern on b128 reads
    for (int idx = tid; idx < 4096; idx += 256) {
      int c = idx & 127, k = idx >> 7;
      int gc = cbase + (c < cols ? c : 0);
      S[4224 + k * UTP + c + ((c >> 5) << 2)] = A[(size_t)(kb + k) * NN + gc];
    }
    __syncthreads();
#pragma unroll 8
    for (int k = 0; k < 32; ++k) {
      const float* lp = &S[k * LTP + rr];
      const float* up = &S[4224 + k * UTP + cs0];
      float4 a0 = *(const float4*)lp;
      float4 a1 = *(const float4*)(lp + 4);
      float4 b0 = *(const float4*)up;
      float4 b1 = *(const float4*)(up + 4);
      float af[8] = {a0.x, a0.y, a0.z, a0.w, a1.x, a1.y, a1.z, a1.w};
      float bf[8] = {b0.x, b0.y, b0.z, b0.w, b1.x, b1.y, b1.z, b1.w};
#pragma unroll
      for (int i = 0; i < 8; ++i)
#pragma unroll
        for (int j = 0; j < 8; ++j) acc[i][j] += af[i] * bf[j];
    }
  }

  bool special = (txt == 0 && tyt == 0);
  if (!special) {
    if (cc < cols) {
#pragma unroll
      for (int i = 0; i < 8; ++i) {
        int r = rr + i;
        if (r < rows) {
          float4* p = (float4*)&A[(size_t)(rbase + r) * NN + cbase + cc];
          float4 v0 = p[0], v1 = p[1];
          v0.x -= acc[i][0]; v0.y -= acc[i][1]; v0.z -= acc[i][2]; v0.w -= acc[i][3];
          v1.x -= acc[i][4]; v1.y -= acc[i][5]; v1.z -= acc[i][6]; v1.w -= acc[i][7];
          p[0] = v0; p[1] = v1;
        }
      }
    }
    return;
  }
  // special block: top-left 64x64 quadrant IS the next diagonal block.
  __syncthreads();            // all waves done reading staging; reuse S as T
  float* T = S;               // 64x64, pitch TP
  if (cc < cols) {
#pragma unroll
    for (int i = 0; i < 8; ++i) {
      int r = rr + i;
      if (r < rows) {
        float4* p = (float4*)&A[(size_t)(rbase + r) * NN + cbase + cc];
        float4 v0 = p[0], v1 = p[1];
        v0.x -= acc[i][0]; v0.y -= acc[i][1]; v0.z -= acc[i][2]; v0.w -= acc[i][3];
        v1.x -= acc[i][4]; v1.y -= acc[i][5]; v1.z -= acc[i][6]; v1.w -= acc[i][7];
        if (r < 64 && cc < 64) {
          float* t = &T[r * TP + cc];
          t[0] = v0.x; t[1] = v0.y; t[2] = v0.z; t[3] = v0.w;
          t[4] = v1.x; t[5] = v1.y; t[6] = v1.z; t[7] = v1.w;
        } else {
          p[0] = v0; p[1] = v1;
        }
      }
    }
  }
  __syncthreads();
  factor64(T, tid);
  for (int idx = tid; idx < 4096; idx += 256) {
    int r = idx >> 6, c = idx & 63;
    A[(size_t)(base + r) * NN + base + c] = T[r * TP + c];
  }
  if (do_inv)
    invertUL(T, S + 4480, invUb + (size_t)m * 4096, invLb + (size_t)m * 4096, tid);
}

// ---------------- reduction ----------------

__global__ void logdet_kernel(const float* __restrict__ Mb, double* __restrict__ dlog) {
  int m = blockIdx.x;
  const float* A = Mb + (size_t)m * NN * NN;
  double s = 0.0;
  for (int i = threadIdx.x; i < NN; i += 256)
    s += (double)logf(fabsf(A[(size_t)i * NN + i]));
  __shared__ double red[256];
  red[threadIdx.x] = s;
  __syncthreads();
  for (int k = 128; k > 0; k >>= 1) {
    if (threadIdx.x < k) red[threadIdx.x] += red[threadIdx.x + k];
    __syncthreads();
  }
  if (threadIdx.x == 0) dlog[m] = red[0];
}

__global__ void final_kernel(const double* __restrict__ dlog, float* __restrict__ out) {
  if (threadIdx.x == 0) {
    double acc = 0.0;
    for (int b = 0; b < NBATCH; ++b) acc += dlog[b] - dlog[NBATCH + b];
    out[0] = (float)(acc * 0.25);
  }
}

// ---------------- launch ----------------

extern "C" void kernel_launch(void* const* d_in, const int* in_sizes, int n_in,
                              void* d_out, int out_size, void* d_ws, size_t ws_size,
                              hipStream_t stream) {
  const float* scores  = (const float*)d_in[0];
  const float* tm      = (const float*)d_in[1];  // target_mask
  const float* zm      = (const float*)d_in[2];  // z_mask
  const int*   lengths = (const int*)d_in[3];
  float* out = (float*)d_out;

  // ws layout: M (8*2176^2 f32) | cs (8*2176 f32) | dlog (8 f64) | invU | invL
  float* M  = (float*)d_ws;
  float* cs = M + (size_t)NMAT * NN * NN;
  double* dlog = (double*)(cs + (size_t)NMAT * NN);
  float* invU = (float*)(dlog + NMAT);
  float* invL = invU + (size_t)NMAT * 4096;

  init_cs_kernel<<<(NMAT * NN + 255) / 256, 256, 0, stream>>>(cs);
  build_fused<<<dim3((NN + 255) / 256, NN / 64, NBATCH), 256, 0, stream>>>(
      scores, zm, tm, lengths, cs, M);
  diag_fix<<<(NMAT * NN + 255) / 256, 256, 0, stream>>>(lengths, cs, M);
  factor0<<<NMAT, 256, 0, stream>>>(M, invU, invL);

  for (int k0 = 0; k0 + NB < NN; k0 += NB) {
    int rem = NN - k0 - NB;
    panel_gemm<<<dim3(rem / 64, NMAT, 2), 256, 0, stream>>>(M, invU, invL, k0);
    int nt = (rem + 127) / 128;
    trail_gemm<<<dim3(NMAT, nt, nt), 256, 0, stream>>>(
        M, invU, invL, k0, rem > 64 ? 1 : 0);
  }

  logdet_kernel<<<NMAT, 256, 0, stream>>>(M, dlog);
  final_kernel<<<1, 64, 0, stream>>>(dlog, out);
}

// Round 3
// 4872.255 us; speedup vs baseline: 1.1851x; 1.1851x over previous
//
#include <hip/hip_runtime.h>
#include <math.h>

#define NFULL 2177   // 1 + L + S
#define NN    2176   // minor size (NFULL-1), = 17*128
#define NB    64
#define NMAT  8      // 4 batches x {z, target}
#define NBATCH 4
#define TP    65     // pitch of 64x64 factor/inverse tiles in LDS
#define LTP   132    // Lt quarter pitch (128 rows + pad)
#define UTP   188    // Ut quarter pitch (128 cols + 4-per-8 skew)
#define QL    (16 * LTP)          // 2112 floats
#define QU    (16 * UTP)          // 3008 floats
#define QBUF  (QL + QU)           // 5120 floats per quarter buffer
#define SSZ2  (2 * QBUF)          // 10240 floats = 41 KB (double buffer)

// ---------------- build phase ----------------

__global__ void init_cs_kernel(float* __restrict__ cs) {
  int i = blockIdx.x * blockDim.x + threadIdx.x;
  if (i < NMAT * NN) cs[i] = 0.f;
}

// Fused: writes off-diagonal M = -w for both masks while accumulating column
// sums (one atomic per thread per mask). Single pass over scores/zm/tm.
__global__ __launch_bounds__(256) void build_fused(const float* __restrict__ scores,
                                                   const float* __restrict__ zm,
                                                   const float* __restrict__ tm,
                                                   const int* __restrict__ lengths,
                                                   float* __restrict__ cs,
                                                   float* __restrict__ M) {
  int c = blockIdx.x * 256 + threadIdx.x;   // minor column, node j = c+1
  if (c >= NN) return;
  int b = blockIdx.z;
  int len = lengths[b];
  int j = c + 1;
  bool jv = (j < len);
  int r0 = blockIdx.y * 64;                 // minor row base
  size_t sbase = (size_t)b * NFULL * NFULL + j;
  float az = 0.f, at = 0.f;
  if (blockIdx.y == 0 && jv) {              // i = 0 (root row): colsum only
    float e = __expf(scores[sbase]);
    az += e * zm[sbase];
    at += e * tm[sbase];
  }
  size_t mz = (size_t)b * NN * NN + (size_t)r0 * NN + c;
  size_t mt = (size_t)(NBATCH + b) * NN * NN + (size_t)r0 * NN + c;
  for (int rr = 0; rr < 64; ++rr) {
    int i = r0 + rr + 1;
    float vz = 0.f, vt = 0.f;
    if (jv && i < len) {
      size_t off = sbase + (size_t)i * NFULL;
      float e = __expf(scores[off]);
      vz = e * zm[off];
      vt = e * tm[off];
      az += vz;
      at += vt;
    }
    M[mz] = -vz;
    M[mt] = -vt;
    mz += NN;
    mt += NN;
  }
  if (az != 0.f) atomicAdd(&cs[b * NN + c], az);
  if (at != 0.f) atomicAdd(&cs[(NBATCH + b) * NN + c], at);
}

// diagonal: M[c][c] = colsum + pad (identity row/col for invalid nodes)
__global__ void diag_fix(const int* __restrict__ lengths,
                         const float* __restrict__ cs,
                         float* __restrict__ M) {
  int idx = blockIdx.x * 256 + threadIdx.x;
  if (idx >= NMAT * NN) return;
  int mm = idx / NN, c = idx - mm * NN;
  int len = lengths[mm & 3];
  float pad = (c + 1 < len) ? 0.f : 1.f;
  M[(size_t)mm * NN * NN + (size_t)c * NN + c] = cs[idx] + pad;
}

// ---------------- LU building blocks ----------------

// Factor 64x64 block in LDS (pitch TP), L unit-lower \ U upper. 256 threads.
// Thread owns column c = tid&63, row-residue g = tid>>6 (rows r == g mod 4).
__device__ __forceinline__ void factor64(float* T, int tid) {
  int c = tid & 63, g = tid >> 6;
  for (int j = 0; j < 63; ++j) {
    float inv = 1.0f / T[j * TP + j];
    int rs = j + 1 + ((g - j - 1) & 3);   // smallest r > j with r == g (mod 4)
    if (c == j) {
      for (int r = rs; r < 64; r += 4) T[r * TP + j] *= inv;
    }
    __syncthreads();
    if (c > j) {
      float ujc = T[j * TP + c];
      for (int r = rs; r < 64; r += 4) T[r * TP + c] -= T[r * TP + j] * ujc;
    }
    __syncthreads();
  }
}

// Parallel blocked inversion of L (unit-lower) and U from factored T (pitch TP).
// 2x2 split: four 32x32 triangular inversions (column-parallel across lanes),
// corner blocks via 32^3 GEMMs over all 256 threads. Results to global.
__device__ void invert64(const float* T, float* X,
                         float* __restrict__ invUg,
                         float* __restrict__ invLg, int tid) {
  // ---- U phase: diag blocks ----
  if (tid < 64) {
    int o = (tid >> 5) * 32, jj = tid & 31, j = o + jj;
    X[(o + jj) * TP + j] = 1.0f / T[(o + jj) * TP + (o + jj)];
    for (int i = jj - 1; i >= 0; --i) {
      float s = 0.f;
      for (int t = i + 1; t <= jj; ++t)
        s += T[(o + i) * TP + (o + t)] * X[(o + t) * TP + j];
      X[(o + i) * TP + j] = -s / T[(o + i) * TP + (o + i)];
    }
  }
  __syncthreads();
  // W = U01 * iU11 into scratch X[32:64][0:32]
  for (int e = tid; e < 1024; e += 256) {
    int i = e >> 5, j = e & 31;
    float s = 0.f;
    for (int t = 0; t <= j; ++t)
      s += T[i * TP + 32 + t] * X[(32 + t) * TP + 32 + j];
    X[(32 + i) * TP + j] = s;
  }
  __syncthreads();
  // iU01 = -iU00 * W into X[0:32][32:64]
  for (int e = tid; e < 1024; e += 256) {
    int i = e >> 5, j = e & 31;
    float s = 0.f;
    for (int t = i; t < 32; ++t)
      s += X[i * TP + t] * X[(32 + t) * TP + j];
    X[i * TP + 32 + j] = -s;
  }
  __syncthreads();
  for (int e = tid; e < 4096; e += 256) {
    int i = e >> 6, j = e & 63;
    float v = 0.f;
    if (i < 32 && j >= 32) v = X[i * TP + j];
    else if ((i >> 5) == (j >> 5) && i <= j) v = X[i * TP + j];
    invUg[e] = v;
  }
  __syncthreads();
  // ---- L phase (unit lower): diag blocks ----
  if (tid < 64) {
    int o = (tid >> 5) * 32, jj = tid & 31, j = o + jj;
    X[(o + jj) * TP + j] = 1.0f;
    for (int i = jj + 1; i < 32; ++i) {
      float s = 0.f;
      for (int t = jj; t < i; ++t)
        s += T[(o + i) * TP + (o + t)] * X[(o + t) * TP + j];
      X[(o + i) * TP + j] = -s;
    }
  }
  __syncthreads();
  // W = L10 * iL00 into scratch X[0:32][32:64]
  for (int e = tid; e < 1024; e += 256) {
    int i = e >> 5, j = e & 31;
    float s = 0.f;
    for (int t = j; t < 32; ++t)
      s += T[(32 + i) * TP + t] * X[t * TP + j];
    X[i * TP + 32 + j] = s;
  }
  __syncthreads();
  // iL10 = -iL11 * W into X[32:64][0:32]
  for (int e = tid; e < 1024; e += 256) {
    int i = e >> 5, j = e & 31;
    float s = 0.f;
    for (int t = 0; t <= i; ++t)
      s += X[(32 + i) * TP + 32 + t] * X[t * TP + 32 + j];
    X[(32 + i) * TP + j] = -s;
  }
  __syncthreads();
  for (int e = tid; e < 4096; e += 256) {
    int i = e >> 6, j = e & 63;
    float v = 0.f;
    if (i >= 32 && j < 32) v = X[i * TP + j];
    else if ((i >> 5) == (j >> 5)) v = (i > j) ? X[i * TP + j] : (i == j ? 1.f : 0.f);
    invLg[e] = v;
  }
}

// factor + invert diagonal block 0 (only standalone factor launch)
__global__ __launch_bounds__(256) void factor0(float* __restrict__ Mb,
                                               float* __restrict__ invUb,
                                               float* __restrict__ invLb) {
  __shared__ float T[64 * TP];
  __shared__ float X[64 * TP];
  int m = blockIdx.x, tid = threadIdx.x;
  float* A = Mb + (size_t)m * NN * NN;
  for (int idx = tid; idx < 4096; idx += 256)
    T[(idx >> 6) * TP + (idx & 63)] = A[(size_t)(idx >> 6) * NN + (idx & 63)];
  __syncthreads();
  factor64(T, tid);
  for (int idx = tid; idx < 4096; idx += 256)
    A[(size_t)(idx >> 6) * NN + (idx & 63)] = T[(idx >> 6) * TP + (idx & 63)];
  invert64(T, X, invUb + (size_t)m * 4096, invLb + (size_t)m * 4096, tid);
}

// Panel update as GEMM: role 0 -> L21 = A21 * invU ; role 1 -> U12 = invL * A12
__global__ __launch_bounds__(256) void panel_gemm(float* __restrict__ Mb,
                                                  const float* __restrict__ invUb,
                                                  const float* __restrict__ invLb,
                                                  int k0) {
  __shared__ float Aa[64][68];  // Aa[k][r]
  __shared__ float Bb[64][68];  // Bb[k][c]
  int m = blockIdx.y, role = blockIdx.z, tid = threadIdx.x;
  float* A = Mb + (size_t)m * NN * NN;
  int obase = k0 + 64 + blockIdx.x * 64;
  if (role == 0) {
    const float* invU = invUb + (size_t)m * 4096;
    for (int idx = tid; idx < 4096; idx += 256) {
      int r = idx >> 6, k = idx & 63;
      Aa[k][r] = A[(size_t)(obase + r) * NN + (k0 + k)];
    }
    for (int idx = tid; idx < 4096; idx += 256)
      Bb[idx >> 6][idx & 63] = invU[idx];
  } else {
    const float* invL = invLb + (size_t)m * 4096;
    for (int idx = tid; idx < 4096; idx += 256) {
      int r = idx >> 6, k = idx & 63;
      Aa[k][r] = invL[(r << 6) + k];
    }
    for (int idx = tid; idx < 4096; idx += 256) {
      int k = idx >> 6, c = idx & 63;
      Bb[k][c] = A[(size_t)(k0 + k) * NN + (obase + c)];
    }
  }
  __syncthreads();
  int c0 = (tid & 15) << 2;
  int r0 = (tid >> 4) << 2;
  float acc[4][4];
#pragma unroll
  for (int i = 0; i < 4; ++i)
#pragma unroll
    for (int jj = 0; jj < 4; ++jj) acc[i][jj] = 0.f;
#pragma unroll 8
  for (int k = 0; k < 64; ++k) {
    float4 a  = *(const float4*)&Aa[k][r0];
    float4 bv = *(const float4*)&Bb[k][c0];
    acc[0][0] += a.x * bv.x; acc[0][1] += a.x * bv.y; acc[0][2] += a.x * bv.z; acc[0][3] += a.x * bv.w;
    acc[1][0] += a.y * bv.x; acc[1][1] += a.y * bv.y; acc[1][2] += a.y * bv.z; acc[1][3] += a.y * bv.w;
    acc[2][0] += a.z * bv.x; acc[2][1] += a.z * bv.y; acc[2][2] += a.z * bv.z; acc[2][3] += a.z * bv.w;
    acc[3][0] += a.w * bv.x; acc[3][1] += a.w * bv.y; acc[3][2] += a.w * bv.z; acc[3][3] += a.w * bv.w;
  }
  if (role == 0) {
#pragma unroll
    for (int i = 0; i < 4; ++i) {
      float4 v = make_float4(acc[i][0], acc[i][1], acc[i][2], acc[i][3]);
      *(float4*)&A[(size_t)(obase + r0 + i) * NN + (k0 + c0)] = v;
    }
  } else {
#pragma unroll
    for (int i = 0; i < 4; ++i) {
      float4 v = make_float4(acc[i][0], acc[i][1], acc[i][2], acc[i][3]);
      *(float4*)&A[(size_t)(k0 + r0 + i) * NN + (obase + c0)] = v;
    }
  }
}

// ---- trail staging helpers (reg-staged, software-pipelined) ----

__device__ __forceinline__ void load_quarter_regs(const float* __restrict__ A,
                                                  int rbase, int cbase, int rows, int cols,
                                                  int kb, float* lr, float* ur, int tid) {
#pragma unroll
  for (int s = 0; s < 8; ++s) {
    int idx = tid + s * 256;
    int k = idx & 15, r = idx >> 4;
    int gr = rbase + (r < rows ? r : 0);
    lr[s] = A[(size_t)gr * NN + kb + k];
  }
#pragma unroll
  for (int s = 0; s < 8; ++s) {
    int idx = tid + s * 256;
    int c = idx & 127, k = idx >> 7;
    int gc = cbase + (c < cols ? c : 0);
    ur[s] = A[(size_t)(kb + k) * NN + gc];
  }
}

__device__ __forceinline__ void write_quarter_lds(float* __restrict__ S,
                                                  const float* lr, const float* ur, int tid) {
#pragma unroll
  for (int s = 0; s < 8; ++s) {
    int idx = tid + s * 256;
    int k = idx & 15, r = idx >> 4;
    S[k * LTP + r] = lr[s];
  }
#pragma unroll
  for (int s = 0; s < 8; ++s) {
    int idx = tid + s * 256;
    int c = idx & 127, k = idx >> 7;
    S[QL + k * UTP + c + 4 * (c >> 3)] = ur[s];
  }
}

// Trailing update A22 -= L21*U12: 128x128 tile per block, 8x8 micro per thread.
// K=64 in four 16-deep quarters, double-buffered LDS; loads for quarter q+1
// issued before computing quarter q (latency hidden under FMA issue).
// blockIdx.x = m so the 8 special (0,0) blocks are dispatched FIRST; their
// fused next-diag factor + parallel inverses hide under the trailing update.
__global__ __launch_bounds__(256, 2) void trail_gemm(float* __restrict__ Mb,
                                                     float* __restrict__ invUb,
                                                     float* __restrict__ invLb,
                                                     int k0, int do_inv) {
  __shared__ float S[SSZ2];
  int m = blockIdx.x;
  int txt = blockIdx.y, tyt = blockIdx.z;
  float* A = Mb + (size_t)m * NN * NN;
  int base = k0 + NB;
  int rem  = NN - base;
  int rbase = base + tyt * 128, cbase = base + txt * 128;
  int rows = rem - tyt * 128; if (rows > 128) rows = 128;
  int cols = rem - txt * 128; if (cols > 128) cols = 128;
  int tid = threadIdx.x;
  int tx = tid & 15, ty = tid >> 4;
  int rr = ty * 8, cc = tx * 8;
  int ccs = 12 * tx;            // skewed Ut offset: cc + 4*(cc>>3)
  float acc[8][8];
#pragma unroll
  for (int i = 0; i < 8; ++i)
#pragma unroll
    for (int j = 0; j < 8; ++j) acc[i][j] = 0.f;

  float lr[8], ur[8];
  load_quarter_regs(A, rbase, cbase, rows, cols, k0, lr, ur, tid);
  write_quarter_lds(S, lr, ur, tid);
  __syncthreads();

#pragma unroll
  for (int q = 0; q < 4; ++q) {
    if (q < 3)
      load_quarter_regs(A, rbase, cbase, rows, cols, k0 + (q + 1) * 16, lr, ur, tid);
    const float* Sc = S + (q & 1) * QBUF;
#pragma unroll
    for (int k = 0; k < 16; ++k) {
      const float* lp = &Sc[k * LTP + rr];
      const float* up = &Sc[QL + k * UTP + ccs];
      float4 a0 = *(const float4*)lp;
      float4 a1 = *(const float4*)(lp + 4);
      float4 b0 = *(const float4*)up;
      float4 b1 = *(const float4*)(up + 4);
      acc[0][0] += a0.x * b0.x; acc[0][1] += a0.x * b0.y; acc[0][2] += a0.x * b0.z; acc[0][3] += a0.x * b0.w;
      acc[0][4] += a0.x * b1.x; acc[0][5] += a0.x * b1.y; acc[0][6] += a0.x * b1.z; acc[0][7] += a0.x * b1.w;
      acc[1][0] += a0.y * b0.x; acc[1][1] += a0.y * b0.y; acc[1][2] += a0.y * b0.z; acc[1][3] += a0.y * b0.w;
      acc[1][4] += a0.y * b1.x; acc[1][5] += a0.y * b1.y; acc[1][6] += a0.y * b1.z; acc[1][7] += a0.y * b1.w;
      acc[2][0] += a0.z * b0.x; acc[2][1] += a0.z * b0.y; acc[2][2] += a0.z * b0.z; acc[2][3] += a0.z * b0.w;
      acc[2][4] += a0.z * b1.x; acc[2][5] += a0.z * b1.y; acc[2][6] += a0.z * b1.z; acc[2][7] += a0.z * b1.w;
      acc[3][0] += a0.w * b0.x; acc[3][1] += a0.w * b0.y; acc[3][2] += a0.w * b0.z; acc[3][3] += a0.w * b0.w;
      acc[3][4] += a0.w * b1.x; acc[3][5] += a0.w * b1.y; acc[3][6] += a0.w * b1.z; acc[3][7] += a0.w * b1.w;
      acc[4][0] += a1.x * b0.x; acc[4][1] += a1.x * b0.y; acc[4][2] += a1.x * b0.z; acc[4][3] += a1.x * b0.w;
      acc[4][4] += a1.x * b1.x; acc[4][5] += a1.x * b1.y; acc[4][6] += a1.x * b1.z; acc[4][7] += a1.x * b1.w;
      acc[5][0] += a1.y * b0.x; acc[5][1] += a1.y * b0.y; acc[5][2] += a1.y * b0.z; acc[5][3] += a1.y * b0.w;
      acc[5][4] += a1.y * b1.x; acc[5][5] += a1.y * b1.y; acc[5][6] += a1.y * b1.z; acc[5][7] += a1.y * b1.w;
      acc[6][0] += a1.z * b0.x; acc[6][1] += a1.z * b0.y; acc[6][2] += a1.z * b0.z; acc[6][3] += a1.z * b0.w;
      acc[6][4] += a1.z * b1.x; acc[6][5] += a1.z * b1.y; acc[6][6] += a1.z * b1.z; acc[6][7] += a1.z * b1.w;
      acc[7][0] += a1.w * b0.x; acc[7][1] += a1.w * b0.y; acc[7][2] += a1.w * b0.z; acc[7][3] += a1.w * b0.w;
      acc[7][4] += a1.w * b1.x; acc[7][5] += a1.w * b1.y; acc[7][6] += a1.w * b1.z; acc[7][7] += a1.w * b1.w;
    }
    __syncthreads();
    if (q < 3) {
      write_quarter_lds(S + ((q + 1) & 1) * QBUF, lr, ur, tid);
      __syncthreads();
    }
  }

  bool special = (txt == 0 && tyt == 0);
  if (!special) {
    if (cc < cols) {
#pragma unroll
      for (int i = 0; i < 8; ++i) {
        int r = rr + i;
        if (r < rows) {
          float4* p = (float4*)&A[(size_t)(rbase + r) * NN + cbase + cc];
          float4 v0 = p[0], v1 = p[1];
          v0.x -= acc[i][0]; v0.y -= acc[i][1]; v0.z -= acc[i][2]; v0.w -= acc[i][3];
          v1.x -= acc[i][4]; v1.y -= acc[i][5]; v1.z -= acc[i][6]; v1.w -= acc[i][7];
          p[0] = v0; p[1] = v1;
        }
      }
    }
    return;
  }
  // special block: top-left 64x64 quadrant IS the next diagonal block.
  float* T = S;            // 64x64, pitch TP (4160 floats)
  float* X = S + 4224;     // 64x64, pitch TP
  if (cc < cols) {
#pragma unroll
    for (int i = 0; i < 8; ++i) {
      int r = rr + i;
      if (r < rows) {
        float4* p = (float4*)&A[(size_t)(rbase + r) * NN + cbase + cc];
        float4 v0 = p[0], v1 = p[1];
        v0.x -= acc[i][0]; v0.y -= acc[i][1]; v0.z -= acc[i][2]; v0.w -= acc[i][3];
        v1.x -= acc[i][4]; v1.y -= acc[i][5]; v1.z -= acc[i][6]; v1.w -= acc[i][7];
        if (r < 64 && cc < 64) {
          float* t = &T[r * TP + cc];
          t[0] = v0.x; t[1] = v0.y; t[2] = v0.z; t[3] = v0.w;
          t[4] = v1.x; t[5] = v1.y; t[6] = v1.z; t[7] = v1.w;
        } else {
          p[0] = v0; p[1] = v1;
        }
      }
    }
  }
  __syncthreads();
  factor64(T, tid);
  for (int idx = tid; idx < 4096; idx += 256) {
    int r = idx >> 6, c = idx & 63;
    A[(size_t)(base + r) * NN + base + c] = T[r * TP + c];
  }
  if (do_inv)
    invert64(T, X, invUb + (size_t)m * 4096, invLb + (size_t)m * 4096, tid);
}

// ---------------- reduction ----------------

__global__ void logdet_kernel(const float* __restrict__ Mb, double* __restrict__ dlog) {
  int m = blockIdx.x;
  const float* A = Mb + (size_t)m * NN * NN;
  double s = 0.0;
  for (int i = threadIdx.x; i < NN; i += 256)
    s += (double)logf(fabsf(A[(size_t)i * NN + i]));
  __shared__ double red[256];
  red[threadIdx.x] = s;
  __syncthreads();
  for (int k = 128; k > 0; k >>= 1) {
    if (threadIdx.x < k) red[threadIdx.x] += red[threadIdx.x + k];
    __syncthreads();
  }
  if (threadIdx.x == 0) dlog[m] = red[0];
}

__global__ void final_kernel(const double* __restrict__ dlog, float* __restrict__ out) {
  if (threadIdx.x == 0) {
    double acc = 0.0;
    for (int b = 0; b < NBATCH; ++b) acc += dlog[b] - dlog[NBATCH + b];
    out[0] = (float)(acc * 0.25);
  }
}

// ---------------- launch ----------------

extern "C" void kernel_launch(void* const* d_in, const int* in_sizes, int n_in,
                              void* d_out, int out_size, void* d_ws, size_t ws_size,
                              hipStream_t stream) {
  const float* scores  = (const float*)d_in[0];
  const float* tm      = (const float*)d_in[1];  // target_mask
  const float* zm      = (const float*)d_in[2];  // z_mask
  const int*   lengths = (const int*)d_in[3];
  float* out = (float*)d_out;

  // ws layout: M (8*2176^2 f32) | cs (8*2176 f32) | dlog (8 f64) | invU | invL
  float* M  = (float*)d_ws;
  float* cs = M + (size_t)NMAT * NN * NN;
  double* dlog = (double*)(cs + (size_t)NMAT * NN);
  float* invU = (float*)(dlog + NMAT);
  float* invL = invU + (size_t)NMAT * 4096;

  init_cs_kernel<<<(NMAT * NN + 255) / 256, 256, 0, stream>>>(cs);
  build_fused<<<dim3((NN + 255) / 256, NN / 64, NBATCH), 256, 0, stream>>>(
      scores, zm, tm, lengths, cs, M);
  diag_fix<<<(NMAT * NN + 255) / 256, 256, 0, stream>>>(lengths, cs, M);
  factor0<<<NMAT, 256, 0, stream>>>(M, invU, invL);

  for (int k0 = 0; k0 + NB < NN; k0 += NB) {
    int rem = NN - k0 - NB;
    panel_gemm<<<dim3(rem / 64, NMAT, 2), 256, 0, stream>>>(M, invU, invL, k0);
    int nt = (rem + 127) / 128;
    trail_gemm<<<dim3(NMAT, nt, nt), 256, 0, stream>>>(
        M, invU, invL, k0, rem > 64 ? 1 : 0);
  }

  logdet_kernel<<<NMAT, 256, 0, stream>>>(M, dlog);
  final_kernel<<<1, 64, 0, stream>>>(dlog, out);
}